// Round 23
// baseline (367.424 us; speedup 1.0000x reference)
//
#include <hip/hip_runtime.h>
#include <stdint.h>

// ---------------------------------------------------------------------------
// LawinAttn fused pipeline for MI355X (gfx950).
// k0 prep (pm_W+I fold, lane-major pmw2), k1 posmix+query-transpose (grid
// 4096, 18.4KB LDS), k2 projections (128x128, BK=32, triple-buffered
// counted-vmcnt + XCD decode + setprio), k34 attention+out FUSED (y stays
// in LDS: saves 67MB round-trip + launch + stage).
// Rules: static acc indexing; no min-waves; B stays in gload_lds pipeline.
// ---------------------------------------------------------------------------

typedef short bf16x8 __attribute__((ext_vector_type(8)));
typedef float f32x4 __attribute__((ext_vector_type(4)));

#define MFMA16(a, b, c) __builtin_amdgcn_mfma_f32_16x16x32_bf16((a), (b), (c), 0, 0, 0)

// ws byte offsets
#define WS_W     0u           // 4 x 131072 bf16 weights: [theta|phi|g|out]
#define WS_BN    1048576u     // 2560 f32
#define WS_PMW   1058816u     // 262144 bf16 (pm_W + I, lane-major pmw2)
#define WS_CTX2  2097152u     // 1024*64*512 bf16 q-major ctx2
#define WS_THQ   69206016u    // 3 x 1024*64*256 bf16 theta/phi head-major, g d-major

__device__ __forceinline__ unsigned short f2bf(float f) {
    union { float f; unsigned int i; } v; v.f = f;
    unsigned int r = v.i + 0x7fffu + ((v.i >> 16) & 1u);   // RNE
    return (unsigned short)(r >> 16);
}
__device__ __forceinline__ unsigned cvtpk(float lo, float hi) {
    unsigned r;
    asm("v_cvt_pk_bf16_f32 %0, %1, %2" : "=v"(r) : "v"(lo), "v"(hi));
    return r;
}

// ---------------------------------------------------------------------------
// k0: weights -> bf16 in ws.  pm_W: lane-major pmw2[h][nt][ks][lane][8] =
// pm_W[h][q=nt*16+(lane&15)][p=ks*32+(lane>>4)*8+j] + (q==p).
// BN (gamma,beta,mean,var) -> (scale,shift).
// ---------------------------------------------------------------------------
__global__ __launch_bounds__(256) void k0_prep(char* __restrict__ ws,
    const float* __restrict__ thW, const float* __restrict__ phW,
    const float* __restrict__ gW,  const float* __restrict__ outW,
    const float* __restrict__ pmW,
    const float* __restrict__ th_g, const float* __restrict__ th_b,
    const float* __restrict__ th_m, const float* __restrict__ th_v,
    const float* __restrict__ ph_g, const float* __restrict__ ph_b,
    const float* __restrict__ ph_m, const float* __restrict__ ph_v,
    const float* __restrict__ g_g,  const float* __restrict__ g_b,
    const float* __restrict__ g_m,  const float* __restrict__ g_v,
    const float* __restrict__ o_g,  const float* __restrict__ o_b,
    const float* __restrict__ o_m,  const float* __restrict__ o_v) {
    int i = blockIdx.x * 256 + threadIdx.x;
    if (i < 524288) {
        int mat = i >> 17, el = i & 131071;
        const float* src = (mat == 0) ? thW : (mat == 1) ? phW : (mat == 2) ? gW : outW;
        ((unsigned short*)ws)[mat * 131072 + el] = f2bf(src[el]);
    } else if (i < 786432) {
        int el = i - 524288;
        int h = el >> 12, rem = el & 4095;
        int nt = rem >> 10, rem2 = rem & 1023;
        int ks = rem2 >> 9, rem3 = rem2 & 511;
        int lane = rem3 >> 3, j = rem3 & 7;
        int gg = lane >> 4, li2 = lane & 15;
        int q = nt * 16 + li2, p = ks * 32 + gg * 8 + j;
        float idt = (q == p) ? 1.0f : 0.0f;  // +I fold
        ((unsigned short*)(ws + WS_PMW))[el] = f2bf(pmW[h * 4096 + q * 64 + p] + idt);
    } else if (i < 786432 + 2560) {
        int j = i - 786432;
        float* bn = (float*)(ws + WS_BN);
        float v;
        if (j < 256)        { int c = j;        v = th_g[c] * rsqrtf(th_v[c] + 1e-5f); }
        else if (j < 512)   { int c = j - 256;  float s = th_g[c] * rsqrtf(th_v[c] + 1e-5f); v = th_b[c] - th_m[c] * s; }
        else if (j < 768)   { int c = j - 512;  v = ph_g[c] * rsqrtf(ph_v[c] + 1e-5f); }
        else if (j < 1024)  { int c = j - 768;  float s = ph_g[c] * rsqrtf(ph_v[c] + 1e-5f); v = ph_b[c] - ph_m[c] * s; }
        else if (j < 1280)  { int c = j - 1024; v = g_g[c] * rsqrtf(g_v[c] + 1e-5f); }
        else if (j < 1536)  { int c = j - 1280; float s = g_g[c] * rsqrtf(g_v[c] + 1e-5f); v = g_b[c] - g_m[c] * s; }
        else if (j < 2048)  { int c = j - 1536; v = o_g[c] * rsqrtf(o_v[c] + 1e-5f); }
        else                { int c = j - 2048; float s = o_g[c] * rsqrtf(o_v[c] + 1e-5f); v = o_b[c] - o_m[c] * s; }
        bn[j] = v;
    }
}

// ---------------------------------------------------------------------------
// k1: posmix + query transpose.  Grid 4096: block = (npair, s8 64-ch slice).
// LDS stg[2n][64q][72] = 18.4KB.  ctx2 = ctx_h @ (pm_W^T + I) + pm_b;
// B-frags from lane-major pmw2 (coalesced 1KB wave loads).
// ---------------------------------------------------------------------------
__global__ __launch_bounds__(256) void k1_posmix(const float* __restrict__ ctx,
                                                 const float* __restrict__ pm_b,
                                                 const float* __restrict__ query,
                                                 unsigned short* __restrict__ qT,
                                                 char* __restrict__ ws) {
    __shared__ __align__(16) unsigned short stg[2 * 64 * 72];  // pitch 72
    const unsigned short* pmw = (const unsigned short*)(ws + WS_PMW);
    unsigned short* ctx2 = (unsigned short*)(ws + WS_CTX2);
    int t = threadIdx.x, w = t >> 6, l = t & 63, g = l >> 4, li = l & 15;
    int np = blockIdx.x >> 3, s8 = blockIdx.x & 7;
    int n0 = np * 2;
    int ni = li >> 3, cc = li & 7;  // A row = (n_i, cc)

    // ---- phase 1: posmix over this slice's 8 heads (2 per wave) ----
#pragma unroll
    for (int hi = 0; hi < 2; ++hi) {
        int h = s8 * 8 + w * 2 + hi;
        const float* arow = ctx + (size_t)(n0 + ni) * 32768 + (size_t)(h * 8 + cc) * 64;
        bf16x8 a[2];
#pragma unroll
        for (int ks = 0; ks < 2; ++ks) {
            float4 f0 = *(const float4*)(arow + ks * 32 + g * 8);
            float4 f1 = *(const float4*)(arow + ks * 32 + g * 8 + 4);
            bf16x8 av;
            av[0] = (short)f2bf(f0.x); av[1] = (short)f2bf(f0.y);
            av[2] = (short)f2bf(f0.z); av[3] = (short)f2bf(f0.w);
            av[4] = (short)f2bf(f1.x); av[5] = (short)f2bf(f1.y);
            av[6] = (short)f2bf(f1.z); av[7] = (short)f2bf(f1.w);
            a[ks] = av;
        }
#pragma unroll
        for (int nt = 0; nt < 4; ++nt) {
            int q = nt * 16 + li;
            const unsigned short* base = pmw + h * 4096 + nt * 1024;
            bf16x8 b0 = *(const bf16x8*)(base + l * 8);          // ks=0, coalesced
            bf16x8 b1 = *(const bf16x8*)(base + 512 + l * 8);    // ks=1, coalesced
            f32x4 acc = {0.f, 0.f, 0.f, 0.f};
            acc = MFMA16(a[0], b0, acc);
            acc = MFMA16(a[1], b1, acc);
            float pb = pm_b[h * 64 + q];
#pragma unroll
            for (int rr = 0; rr < 4; ++rr) {
                int row = 4 * g + rr; int n2 = row >> 3, c2 = row & 7;
                stg[n2 * 4608 + q * 72 + (w * 2 + hi) * 8 + c2] = f2bf(acc[rr] + pb);
            }
        }
    }
    __syncthreads();
#pragma unroll
    for (int it = 0; it < 4; ++it) {
        int ci = it * 256 + t;
        int n2 = ci >> 9, q = (ci >> 3) & 63, seg = ci & 7;
        uint4 v = *(const uint4*)&stg[n2 * 4608 + q * 72 + seg * 8];
        *(uint4*)(ctx2 + (size_t)(n0 + n2) * 32768 + (size_t)q * 512 + s8 * 64 + seg * 8) = v;
    }

    // ---- phase 2: query transpose, this slice's 64 channels, both n ----
    __syncthreads();   // stg reuse
#pragma unroll
    for (int it = 0; it < 8; ++it) {
        int ci = it * 256 + t;
        int n2 = ci >> 10, rem = ci & 1023;
        int q = rem & 63, c0 = (rem >> 6) * 4;
        const float* qs = query + (size_t)(n0 + n2) * 32768 + (size_t)s8 * 4096;
        float f0 = qs[(c0 + 0) * 64 + q];
        float f1 = qs[(c0 + 1) * 64 + q];
        float f2 = qs[(c0 + 2) * 64 + q];
        float f3 = qs[(c0 + 3) * 64 + q];
        uint2 pk;
        pk.x = (unsigned)f2bf(f0) | ((unsigned)f2bf(f1) << 16);
        pk.y = (unsigned)f2bf(f2) | ((unsigned)f2bf(f3) << 16);
        *(uint2*)&stg[n2 * 4608 + q * 72 + c0] = pk;
    }
    __syncthreads();
#pragma unroll
    for (int it = 0; it < 4; ++it) {
        int ci = it * 256 + t;
        int n2 = ci >> 9, q = (ci >> 3) & 63, seg = ci & 7;
        uint4 v = *(const uint4*)&stg[n2 * 4608 + q * 72 + seg * 8];
        *(uint4*)(qT + (size_t)(n0 + n2) * 32768 + (size_t)q * 512 + s8 * 64 + seg * 8) = v;
    }
}

// ---------------------------------------------------------------------------
// k2: projections, 128x128 C-tile, BK=32 (16 K-steps).  TRIPLE-buffered
// counted-vmcnt pipeline; XCD-aware decode.  LDS 48KB.  setprio.
// Output: theta/phi head-major [n][h][q][4d]; g D-MAJOR [n][h][d][k].
// ---------------------------------------------------------------------------
__global__ __launch_bounds__(256) void k2_proj(char* __restrict__ ws,
                                               const unsigned short* __restrict__ qT) {
    __shared__ __align__(16) unsigned short lds[24576];  // A0|A1|A2 | B0|B1|B2 (4096 ea)
    int bid = blockIdx.x;
    int c8 = bid & 7, m = bid >> 3;
    int np = c8 * 64 + m / 6, r6 = m % 6;      // same A-panel -> same XCD
    int mat = r6 >> 1;
    int och0 = (r6 & 1) * 128;
    int n0 = np * 2;
    const unsigned short* W = (const unsigned short*)ws + (size_t)mat * 131072;
    const float* bnm = (const float*)(ws + WS_BN) + mat * 512;
    unsigned short* outp = (unsigned short*)(ws + WS_THQ + (size_t)mat * 33554432u);
    const unsigned short* X = (mat == 0) ? qT : (const unsigned short*)(ws + WS_CTX2);
    int t = threadIdx.x, w = t >> 6, l = t & 63, g = l >> 4, li = l & 15;
    int wr = w >> 1, wc = w & 1;

    float sc[4], sh[4];
#pragma unroll
    for (int nti = 0; nti < 4; ++nti) {
        int och = och0 + wc * 64 + nti * 16 + li;
        sc[nti] = bnm[och];
        sh[nti] = bnm[256 + och];
    }

    f32x4 acc[4][4];
#pragma unroll
    for (int mt = 0; mt < 4; ++mt)
#pragma unroll
        for (int nti = 0; nti < 4; ++nti) acc[mt][nti] = (f32x4){0.f, 0.f, 0.f, 0.f};

    auto STAGE = [&](int kt) {
        int s = kt % 3;
        unsigned short* Ab = lds + s * 4096;
        unsigned short* Bb = lds + 12288 + s * 4096;
#pragma unroll
        for (int it = 0; it < 2; ++it) {
            int ci = it * 256 + t;
            int row = ci >> 2, ch = ci & 3;
            int nn = n0 + (row >> 6), q = row & 63;
            const unsigned short* src = X + (size_t)nn * 32768 + (size_t)q * 512 + kt * 32 + ((ch ^ ((row >> 1) & 3)) << 3);
            __builtin_amdgcn_global_load_lds(
                (const __attribute__((address_space(1))) void*)src,
                (__attribute__((address_space(3))) void*)(Ab + ci * 8), 16, 0, 0);
        }
#pragma unroll
        for (int it = 0; it < 2; ++it) {
            int ci = it * 256 + t;
            int row = ci >> 2, ch = ci & 3;
            const unsigned short* src = W + (size_t)(och0 + row) * 512 + kt * 32 + ((ch ^ ((row >> 1) & 3)) << 3);
            __builtin_amdgcn_global_load_lds(
                (const __attribute__((address_space(1))) void*)src,
                (__attribute__((address_space(3))) void*)(Bb + ci * 8), 16, 0, 0);
        }
    };
    auto COMPUTE = [&](int s) {
        const char* Ab = (const char*)(lds + s * 4096);
        const char* Bb = (const char*)(lds + 12288 + s * 4096);
        bf16x8 a[4], b[4];
#pragma unroll
        for (int mt = 0; mt < 4; ++mt) {
            int row = wr * 64 + mt * 16 + li;
            a[mt] = *(const bf16x8*)(Ab + row * 64 + (((g ^ ((row >> 1) & 3))) << 4));
        }
#pragma unroll
        for (int nti = 0; nti < 4; ++nti) {
            int br = wc * 64 + nti * 16 + li;
            b[nti] = *(const bf16x8*)(Bb + br * 64 + (((g ^ ((br >> 1) & 3))) << 4));
        }
        __builtin_amdgcn_s_setprio(1);
#pragma unroll
        for (int mt = 0; mt < 4; ++mt)
#pragma unroll
            for (int nti = 0; nti < 4; ++nti)
                acc[mt][nti] = MFMA16(a[mt], b[nti], acc[mt][nti]);
        __builtin_amdgcn_s_setprio(0);
    };

    STAGE(0);
    STAGE(1);
#pragma unroll 1
    for (int kt = 0; kt < 16; ++kt) {
        if (kt == 15) { asm volatile("s_waitcnt vmcnt(0)" ::: "memory"); }
        else          { asm volatile("s_waitcnt vmcnt(4)" ::: "memory"); }
        __builtin_amdgcn_s_barrier();
        __builtin_amdgcn_sched_barrier(0);
        if (kt < 14) STAGE(kt + 2);
        COMPUTE(kt % 3);
    }
    __syncthreads();   // all waves done reading frags before lds reuse

    unsigned short* stg = lds;
    if (mat != 2) {
        // ---- theta/phi: [128 Mrow][132] -> head-major [n][h][q][4d] ----
#pragma unroll
        for (int mt = 0; mt < 4; ++mt)
#pragma unroll
            for (int nti = 0; nti < 4; ++nti)
#pragma unroll
                for (int rr = 0; rr < 4; ++rr) {
                    int mrow = wr * 64 + mt * 16 + g * 4 + rr;
                    int ocl = wc * 64 + nti * 16 + li;
                    float v = fmaxf(acc[mt][nti][rr] * sc[nti] + sh[nti], 0.f);
                    stg[mrow * 132 + ocl] = f2bf(v);
                }
        __syncthreads();
#pragma unroll
        for (int it = 0; it < 8; ++it) {
            int ci = it * 256 + t;
            int s = ci >> 5, e = ci & 31;
            int nl = s >> 5, hl = s & 31;
            int q0 = e * 2;
            uint2 v0 = *(const uint2*)&stg[(nl * 64 + q0) * 132 + hl * 4];
            uint2 v1 = *(const uint2*)&stg[(nl * 64 + q0 + 1) * 132 + hl * 4];
            uint4 o; o.x = v0.x; o.y = v0.y; o.z = v1.x; o.w = v1.y;
            unsigned short* dst = outp + (size_t)(n0 + nl) * 16384 + (size_t)((och0 >> 2) + hl) * 256 + q0 * 4;
            *(uint4*)dst = o;
        }
    } else {
        // ---- g: transposed stg [128 och][136] -> d-major [n][h][d][k] ----
#pragma unroll
        for (int mt = 0; mt < 4; ++mt)
#pragma unroll
            for (int nti = 0; nti < 4; ++nti)
#pragma unroll
                for (int rr = 0; rr < 4; ++rr) {
                    int mrow = wr * 64 + mt * 16 + g * 4 + rr;
                    int ocl = wc * 64 + nti * 16 + li;
                    float v = fmaxf(acc[mt][nti][rr] * sc[nti] + sh[nti], 0.f);
                    stg[ocl * 136 + mrow] = f2bf(v);
                }
        __syncthreads();
#pragma unroll
        for (int it = 0; it < 8; ++it) {
            int ci = it * 256 + t;
            int nl = (ci >> 10) & 1, hl = (ci >> 5) & 31, dd = (ci >> 3) & 3, q8 = ci & 7;
            uint4 o = *(const uint4*)&stg[(hl * 4 + dd) * 136 + nl * 64 + q8 * 8];
            unsigned short* dst = outp + (size_t)(n0 + nl) * 16384 + (size_t)((och0 >> 2) + hl) * 256 + dd * 64 + q8 * 8;
            *(uint4*)dst = o;
        }
    }
}

// ---------------------------------------------------------------------------
// k34: FUSED attention + out-projection.  Grid 1024 (one n), 4 waves.
// Phase A (= k3): each wave does 16 heads; y goes to LDS yA[h][q][4d]
// (byte = h*512 + q*8; store banks q*2 mod 32 -> 2-way free) instead of
// global.  Phase B (= k4, r9 full-och shape): GEMM 64q x 512och x 256k
// from yA, direct float4 epilogue with query residual.
// LDS 64KB (yA 32K + plds 32K) -> 2 blocks/CU.
// ---------------------------------------------------------------------------
__global__ __launch_bounds__(256) void k34_attn_out(const float* __restrict__ query,
                                                    char* __restrict__ ws,
                                                    float* __restrict__ out) {
    __shared__ __align__(16) unsigned short yA[64 * 256];   // [h][q][4d], 32KB
    __shared__ __align__(16) unsigned short plds[4][4096];  // per-wave P tile, 32KB
    int n = blockIdx.x;
    const unsigned short* th = (const unsigned short*)(ws + WS_THQ) + (size_t)n * 16384;
    const unsigned short* ph = (const unsigned short*)(ws + WS_THQ + 33554432u) + (size_t)n * 16384;
    const unsigned short* gx = (const unsigned short*)(ws + WS_THQ + 67108864u) + (size_t)n * 16384;
    const unsigned short* W = (const unsigned short*)ws + (size_t)3 * 131072;  // out_W bf16
    const float* bn = (const float*)(ws + WS_BN) + 1536;
    int t = threadIdx.x, w = t >> 6, l = t & 63, g = l >> 4, li = l & 15;
    unsigned short* pw = &plds[w][0];
    const float Cs = 0.72134752044f;  // 0.5 (=1/sqrt(dim)) * log2(e)
    f32x4 z4 = {0.f, 0.f, 0.f, 0.f};
    bool zz = (g == 0);
    union FU { uint4 u; bf16x8 v8; };

    // ======== phase A: attention, 16 heads per wave ========
#pragma unroll 1
    for (int hi = 0; hi < 16; ++hi) {
        int h = w * 16 + hi;
        const unsigned short* th_h = th + h * 256;
        const unsigned short* ph_h = ph + h * 256;
        const unsigned short* gx_h = gx + h * 256;   // [d][k] d-major
        bf16x8 a[4], b[4];
#pragma unroll
        for (int mt = 0; mt < 4; ++mt) {   // A = phi rows (k_sp); d at j=0..3, g==0 only
            uint2 v = *(const uint2*)(ph_h + (mt * 16 + li) * 4);
            FU f;
            f.u.x = zz ? v.x : 0u;
            f.u.y = zz ? v.y : 0u;
            f.u.z = 0u; f.u.w = 0u;
            a[mt] = f.v8;
        }
#pragma unroll
        for (int nt = 0; nt < 4; ++nt) {   // B = theta cols (q)
            uint2 v = *(const uint2*)(th_h + (nt * 16 + li) * 4);
            FU f;
            f.u.x = v.x; f.u.y = v.y; f.u.z = 0u; f.u.w = 0u;
            b[nt] = f.v8;
        }
        f32x4 p[4][4];
#pragma unroll
        for (int mt = 0; mt < 4; ++mt)
#pragma unroll
            for (int nt = 0; nt < 4; ++nt) p[mt][nt] = MFMA16(a[mt], b[nt], z4);
        // p[mt][nt][rr] = S[q=nt*16+li][k=mt*16+4g+rr], S >= 0.

        // ---- softmax denom (no max: P = exp2(S*Cs - 46); shift cancels) ----
        float rs[4];
#pragma unroll
        for (int nt = 0; nt < 4; ++nt) {
#pragma unroll
            for (int mt = 0; mt < 4; ++mt) {
                f32x4 tv = p[mt][nt] * Cs + (-46.0f);
                f32x4 ev;
                ev[0] = __builtin_amdgcn_exp2f(tv[0]);
                ev[1] = __builtin_amdgcn_exp2f(tv[1]);
                ev[2] = __builtin_amdgcn_exp2f(tv[2]);
                ev[3] = __builtin_amdgcn_exp2f(tv[3]);
                p[mt][nt] = ev;
            }
            f32x4 s4 = (p[0][nt] + p[1][nt]) + (p[2][nt] + p[3][nt]);
            float sum = (s4[0] + s4[1]) + (s4[2] + s4[3]);
            sum += __shfl_xor(sum, 16);
            sum += __shfl_xor(sum, 32);
            rs[nt] = __builtin_amdgcn_rcpf(sum);
        }

        // ---- P -> bf16 -> wave-private LDS [q][128B], 16B-chunk XOR (q&7) ----
#pragma unroll
        for (int mt = 0; mt < 4; ++mt)
#pragma unroll
            for (int nt = 0; nt < 4; ++nt) {
                int q = nt * 16 + li;
                uint2 dv;
                dv.x = cvtpk(p[mt][nt][0], p[mt][nt][1]);
                dv.y = cvtpk(p[mt][nt][2], p[mt][nt][3]);
                int c16w = 2 * mt + (g >> 1);
                int byt = q * 128 + (((c16w ^ (q & 7)) << 4)) + ((g & 1) << 3);
                *(uint2*)((char*)pw + byt) = dv;
            }

        // ---- PV: y^T[d][q] = mfma(A=g^T[d][k] (global, d-major), B=P^T) ----
        bf16x8 afr0 = *(const bf16x8*)(gx_h + (li & 3) * 64 + g * 8);        // k=0..31
        bf16x8 afr1 = *(const bf16x8*)(gx_h + (li & 3) * 64 + 32 + g * 8);   // k=32..63
        f32x4 yv[4];
#pragma unroll
        for (int qt = 0; qt < 4; ++qt) {
            int q = qt * 16 + li;
            bf16x8 b0 = *(const bf16x8*)((const char*)pw + q * 128 + (((g) ^ (q & 7)) << 4));
            bf16x8 b1 = *(const bf16x8*)((const char*)pw + q * 128 + (((4 + g) ^ (q & 7)) << 4));
            f32x4 acc = MFMA16(afr0, b0, z4);
            acc = MFMA16(afr1, b1, acc);
            yv[qt] = acc;   // lanes 0..15: yv[qt][rr] = y[d=rr][q=qt*16+l]
        }

        // ---- y -> LDS yA[h][q][4d] (byte = h*512 + q*8), banks 2-way free ----
        if (l < 16) {
#pragma unroll
            for (int qt = 0; qt < 4; ++qt) {
                float s = rs[qt];
                uint2 pk;
                pk.x = cvtpk(yv[qt][0] * s, yv[qt][1] * s);
                pk.y = cvtpk(yv[qt][2] * s, yv[qt][3] * s);
                *(uint2*)((char*)yA + h * 512 + (qt * 16 + l) * 8) = pk;
            }
        }
    }
    __syncthreads();

    // ======== phase B: out GEMM (r9 full-och shape, acc[4][8]) ========
    f32x4 acc[4][8];
#pragma unroll
    for (int mt = 0; mt < 4; ++mt)
#pragma unroll
        for (int nti = 0; nti < 8; ++nti) acc[mt][nti] = (f32x4){0.f, 0.f, 0.f, 0.f};

#pragma unroll 1
    for (int kt = 0; kt < 4; ++kt) {
        bf16x8 a[4][2];
#pragma unroll
        for (int mt = 0; mt < 4; ++mt) {
            int q = mt * 16 + li;
            const char* base = (const char*)yA;
            int c0 = kt * 8 + g, c1 = kt * 8 + 4 + g;
            union U { uint2 u[2]; bf16x8 v; };
            U u0, u1;
            u0.u[0] = *(const uint2*)(base + c0 * 1024 + q * 8);
            u0.u[1] = *(const uint2*)(base + c0 * 1024 + 512 + q * 8);
            u1.u[0] = *(const uint2*)(base + c1 * 1024 + q * 8);
            u1.u[1] = *(const uint2*)(base + c1 * 1024 + 512 + q * 8);
            a[mt][0] = u0.v;
            a[mt][1] = u1.v;
        }
#pragma unroll
        for (int nti = 0; nti < 8; ++nti) {
            int och = w * 128 + nti * 16 + li;
            const unsigned short* wr = W + (size_t)och * 256 + kt * 64 + g * 8;
            bf16x8 b0 = *(const bf16x8*)wr;
            bf16x8 b1 = *(const bf16x8*)(wr + 32);
#pragma unroll
            for (int mt = 0; mt < 4; ++mt) {
                acc[mt][nti] = MFMA16(a[mt][0], b0, acc[mt][nti]);
                acc[mt][nti] = MFMA16(a[mt][1], b1, acc[mt][nti]);
            }
        }
    }

    // ---- epilogue: direct float4 (4 consecutive q per lane), no barriers ----
#pragma unroll
    for (int nti = 0; nti < 8; ++nti) {
        int och = w * 128 + nti * 16 + li;
        float sc = bn[och], sb = bn[512 + och];
#pragma unroll
        for (int mt = 0; mt < 4; ++mt) {
            int q0 = mt * 16 + 4 * g;
            size_t idx = (size_t)n * 32768 + (size_t)och * 64 + q0;
            float4 qv = *(const float4*)(query + idx);
            float4 ov;
            ov.x = qv.x + fmaxf(acc[mt][nti][0] * sc + sb, 0.f);
            ov.y = qv.y + fmaxf(acc[mt][nti][1] * sc + sb, 0.f);
            ov.z = qv.z + fmaxf(acc[mt][nti][2] * sc + sb, 0.f);
            ov.w = qv.w + fmaxf(acc[mt][nti][3] * sc + sb, 0.f);
            *(float4*)(out + idx) = ov;
        }
    }
}

// ---------------------------------------------------------------------------
extern "C" void kernel_launch(void* const* d_in, const int* in_sizes, int n_in,
                              void* d_out, int out_size, void* d_ws, size_t ws_size,
                              hipStream_t stream) {
    (void)in_sizes; (void)n_in; (void)out_size; (void)ws_size;
    const float* query   = (const float*)d_in[0];
    const float* context = (const float*)d_in[1];
    const float* pm_W    = (const float*)d_in[2];
    const float* pm_b    = (const float*)d_in[3];
    const float* g_W     = (const float*)d_in[4];
    const float* g_g     = (const float*)d_in[5];
    const float* g_b     = (const float*)d_in[6];
    const float* g_m     = (const float*)d_in[7];
    const float* g_v     = (const float*)d_in[8];
    const float* th_W    = (const float*)d_in[9];
    const float* th_g    = (const float*)d_in[10];
    const float* th_b    = (const float*)d_in[11];
    const float* th_m    = (const float*)d_in[12];
    const float* th_v    = (const float*)d_in[13];
    const float* ph_W    = (const float*)d_in[14];
    const float* ph_g    = (const float*)d_in[15];
    const float* ph_b    = (const float*)d_in[16];
    const float* ph_m    = (const float*)d_in[17];
    const float* ph_v    = (const float*)d_in[18];
    const float* o_W     = (const float*)d_in[19];
    const float* o_g     = (const float*)d_in[20];
    const float* o_b     = (const float*)d_in[21];
    const float* o_m     = (const float*)d_in[22];
    const float* o_v     = (const float*)d_in[23];
    char* ws = (char*)d_ws;
    unsigned short* qT = (unsigned short*)d_out;  // scratch; k34 rewrites d_out

    k0_prep<<<3082, 256, 0, stream>>>(ws, th_W, ph_W, g_W, o_W, pm_W,
                                      th_g, th_b, th_m, th_v,
                                      ph_g, ph_b, ph_m, ph_v,
                                      g_g, g_b, g_m, g_v,
                                      o_g, o_b, o_m, o_v);
    k1_posmix<<<4096, 256, 0, stream>>>(context, pm_b, query, qT, ws);
    k2_proj<<<3072, 256, 0, stream>>>(ws, qT);
    k34_attn_out<<<1024, 256, 0, stream>>>(query, ws, (float*)d_out);
}

// Round 24
// 328.584 us; speedup vs baseline: 1.1182x; 1.1182x over previous
//
#include <hip/hip_runtime.h>
#include <stdint.h>

// ---------------------------------------------------------------------------
// LawinAttn fused pipeline for MI355X (gfx950).  (r22 best configuration;
// r23's k3+k4 fusion regressed -- occupancy loss > traffic saving.)
// k0 prep (pm_W+I fold, lane-major pmw2), k1 posmix+query-transpose (grid
// 4096: block = npair x 64-col slice, LDS 18.4KB), k2 projections (128x128,
// BK=32, triple-buffered counted-vmcnt + XCD decode + setprio), k3
// attention, k4 out proj (och x2).
// Rules: static acc indexing; no min-waves; B stays in gload_lds pipeline.
// ---------------------------------------------------------------------------

typedef short bf16x8 __attribute__((ext_vector_type(8)));
typedef float f32x4 __attribute__((ext_vector_type(4)));

#define MFMA16(a, b, c) __builtin_amdgcn_mfma_f32_16x16x32_bf16((a), (b), (c), 0, 0, 0)

// ws byte offsets
#define WS_W     0u           // 4 x 131072 bf16 weights: [theta|phi|g|out]
#define WS_BN    1048576u     // 2560 f32
#define WS_PMW   1058816u     // 262144 bf16 (pm_W + I, lane-major pmw2)
#define WS_CTX2  2097152u     // 1024*64*512 bf16 q-major ctx2 (later reused as y)
#define WS_THQ   69206016u    // 3 x 1024*64*256 bf16 theta/phi head-major, g d-major
#define WS_YHM   WS_CTX2      // y head-major overlays ctx2 (dead after k2)

__device__ __forceinline__ unsigned short f2bf(float f) {
    union { float f; unsigned int i; } v; v.f = f;
    unsigned int r = v.i + 0x7fffu + ((v.i >> 16) & 1u);   // RNE
    return (unsigned short)(r >> 16);
}
__device__ __forceinline__ unsigned cvtpk(float lo, float hi) {
    unsigned r;
    asm("v_cvt_pk_bf16_f32 %0, %1, %2" : "=v"(r) : "v"(lo), "v"(hi));
    return r;
}

// ---------------------------------------------------------------------------
// k0: weights -> bf16 in ws.  pm_W: lane-major pmw2[h][nt][ks][lane][8] =
// pm_W[h][q=nt*16+(lane&15)][p=ks*32+(lane>>4)*8+j] + (q==p).
// BN (gamma,beta,mean,var) -> (scale,shift).
// ---------------------------------------------------------------------------
__global__ __launch_bounds__(256) void k0_prep(char* __restrict__ ws,
    const float* __restrict__ thW, const float* __restrict__ phW,
    const float* __restrict__ gW,  const float* __restrict__ outW,
    const float* __restrict__ pmW,
    const float* __restrict__ th_g, const float* __restrict__ th_b,
    const float* __restrict__ th_m, const float* __restrict__ th_v,
    const float* __restrict__ ph_g, const float* __restrict__ ph_b,
    const float* __restrict__ ph_m, const float* __restrict__ ph_v,
    const float* __restrict__ g_g,  const float* __restrict__ g_b,
    const float* __restrict__ g_m,  const float* __restrict__ g_v,
    const float* __restrict__ o_g,  const float* __restrict__ o_b,
    const float* __restrict__ o_m,  const float* __restrict__ o_v) {
    int i = blockIdx.x * 256 + threadIdx.x;
    if (i < 524288) {
        int mat = i >> 17, el = i & 131071;
        const float* src = (mat == 0) ? thW : (mat == 1) ? phW : (mat == 2) ? gW : outW;
        ((unsigned short*)ws)[mat * 131072 + el] = f2bf(src[el]);
    } else if (i < 786432) {
        int el = i - 524288;
        int h = el >> 12, rem = el & 4095;
        int nt = rem >> 10, rem2 = rem & 1023;
        int ks = rem2 >> 9, rem3 = rem2 & 511;
        int lane = rem3 >> 3, j = rem3 & 7;
        int gg = lane >> 4, li2 = lane & 15;
        int q = nt * 16 + li2, p = ks * 32 + gg * 8 + j;
        float idt = (q == p) ? 1.0f : 0.0f;  // +I fold
        ((unsigned short*)(ws + WS_PMW))[el] = f2bf(pmW[h * 4096 + q * 64 + p] + idt);
    } else if (i < 786432 + 2560) {
        int j = i - 786432;
        float* bn = (float*)(ws + WS_BN);
        float v;
        if (j < 256)        { int c = j;        v = th_g[c] * rsqrtf(th_v[c] + 1e-5f); }
        else if (j < 512)   { int c = j - 256;  float s = th_g[c] * rsqrtf(th_v[c] + 1e-5f); v = th_b[c] - th_m[c] * s; }
        else if (j < 768)   { int c = j - 512;  v = ph_g[c] * rsqrtf(ph_v[c] + 1e-5f); }
        else if (j < 1024)  { int c = j - 768;  float s = ph_g[c] * rsqrtf(ph_v[c] + 1e-5f); v = ph_b[c] - ph_m[c] * s; }
        else if (j < 1280)  { int c = j - 1024; v = g_g[c] * rsqrtf(g_v[c] + 1e-5f); }
        else if (j < 1536)  { int c = j - 1280; float s = g_g[c] * rsqrtf(g_v[c] + 1e-5f); v = g_b[c] - g_m[c] * s; }
        else if (j < 2048)  { int c = j - 1536; v = o_g[c] * rsqrtf(o_v[c] + 1e-5f); }
        else                { int c = j - 2048; float s = o_g[c] * rsqrtf(o_v[c] + 1e-5f); v = o_b[c] - o_m[c] * s; }
        bn[j] = v;
    }
}

// ---------------------------------------------------------------------------
// k1: posmix + query transpose.  Grid 4096: block = (npair, s8) where s8 is
// a 64-channel slice (8 heads).  LDS stg[2n][64q][72] = 18.4KB -> 8
// blocks/CU.  ctx2 = ctx_h @ (pm_W^T + I) + pm_b; B-frags from lane-major
// pmw2 (coalesced 1KB wave loads).
// ---------------------------------------------------------------------------
__global__ __launch_bounds__(256) void k1_posmix(const float* __restrict__ ctx,
                                                 const float* __restrict__ pm_b,
                                                 const float* __restrict__ query,
                                                 unsigned short* __restrict__ qT,
                                                 char* __restrict__ ws) {
    __shared__ __align__(16) unsigned short stg[2 * 64 * 72];  // pitch 72
    const unsigned short* pmw = (const unsigned short*)(ws + WS_PMW);
    unsigned short* ctx2 = (unsigned short*)(ws + WS_CTX2);
    int t = threadIdx.x, w = t >> 6, l = t & 63, g = l >> 4, li = l & 15;
    int np = blockIdx.x >> 3, s8 = blockIdx.x & 7;
    int n0 = np * 2;
    int ni = li >> 3, cc = li & 7;  // A row = (n_i, cc)

    // ---- phase 1: posmix over this slice's 8 heads (2 per wave) ----
#pragma unroll
    for (int hi = 0; hi < 2; ++hi) {
        int h = s8 * 8 + w * 2 + hi;
        const float* arow = ctx + (size_t)(n0 + ni) * 32768 + (size_t)(h * 8 + cc) * 64;
        bf16x8 a[2];
#pragma unroll
        for (int ks = 0; ks < 2; ++ks) {
            float4 f0 = *(const float4*)(arow + ks * 32 + g * 8);
            float4 f1 = *(const float4*)(arow + ks * 32 + g * 8 + 4);
            bf16x8 av;
            av[0] = (short)f2bf(f0.x); av[1] = (short)f2bf(f0.y);
            av[2] = (short)f2bf(f0.z); av[3] = (short)f2bf(f0.w);
            av[4] = (short)f2bf(f1.x); av[5] = (short)f2bf(f1.y);
            av[6] = (short)f2bf(f1.z); av[7] = (short)f2bf(f1.w);
            a[ks] = av;
        }
#pragma unroll
        for (int nt = 0; nt < 4; ++nt) {
            int q = nt * 16 + li;
            const unsigned short* base = pmw + h * 4096 + nt * 1024;
            bf16x8 b0 = *(const bf16x8*)(base + l * 8);          // ks=0, coalesced
            bf16x8 b1 = *(const bf16x8*)(base + 512 + l * 8);    // ks=1, coalesced
            f32x4 acc = {0.f, 0.f, 0.f, 0.f};
            acc = MFMA16(a[0], b0, acc);
            acc = MFMA16(a[1], b1, acc);
            float pb = pm_b[h * 64 + q];
#pragma unroll
            for (int rr = 0; rr < 4; ++rr) {
                int row = 4 * g + rr; int n2 = row >> 3, c2 = row & 7;
                stg[n2 * 4608 + q * 72 + (w * 2 + hi) * 8 + c2] = f2bf(acc[rr] + pb);
            }
        }
    }
    __syncthreads();
    // copyout 64-col slice: 2n x 64q x 8 uint4-chunks, 4 items/thread
#pragma unroll
    for (int it = 0; it < 4; ++it) {
        int ci = it * 256 + t;
        int n2 = ci >> 9, q = (ci >> 3) & 63, seg = ci & 7;
        uint4 v = *(const uint4*)&stg[n2 * 4608 + q * 72 + seg * 8];
        *(uint4*)(ctx2 + (size_t)(n0 + n2) * 32768 + (size_t)q * 512 + s8 * 64 + seg * 8) = v;
    }

    // ---- phase 2: query transpose, this slice's 64 channels, both n ----
    __syncthreads();   // stg reuse
#pragma unroll
    for (int it = 0; it < 8; ++it) {
        int ci = it * 256 + t;
        int n2 = ci >> 10, rem = ci & 1023;
        int q = rem & 63, c0 = (rem >> 6) * 4;
        const float* qs = query + (size_t)(n0 + n2) * 32768 + (size_t)s8 * 4096;
        float f0 = qs[(c0 + 0) * 64 + q];
        float f1 = qs[(c0 + 1) * 64 + q];
        float f2 = qs[(c0 + 2) * 64 + q];
        float f3 = qs[(c0 + 3) * 64 + q];
        uint2 pk;
        pk.x = (unsigned)f2bf(f0) | ((unsigned)f2bf(f1) << 16);
        pk.y = (unsigned)f2bf(f2) | ((unsigned)f2bf(f3) << 16);
        *(uint2*)&stg[n2 * 4608 + q * 72 + c0] = pk;
    }
    __syncthreads();
#pragma unroll
    for (int it = 0; it < 4; ++it) {
        int ci = it * 256 + t;
        int n2 = ci >> 9, q = (ci >> 3) & 63, seg = ci & 7;
        uint4 v = *(const uint4*)&stg[n2 * 4608 + q * 72 + seg * 8];
        *(uint4*)(qT + (size_t)(n0 + n2) * 32768 + (size_t)q * 512 + s8 * 64 + seg * 8) = v;
    }
}

// ---------------------------------------------------------------------------
// k2: projections, 128x128 C-tile, BK=32 (16 K-steps).  TRIPLE-buffered
// counted-vmcnt pipeline (r13-proven); XCD-aware decode (6 sharers of an
// A-panel on the same XCD).  LDS 48KB.  setprio around MFMA cluster.
// Output: theta/phi head-major [n][h][q][4d]; g D-MAJOR [n][h][d][k].
// ---------------------------------------------------------------------------
__global__ __launch_bounds__(256) void k2_proj(char* __restrict__ ws,
                                               const unsigned short* __restrict__ qT) {
    __shared__ __align__(16) unsigned short lds[24576];  // A0|A1|A2 | B0|B1|B2 (4096 ea)
    int bid = blockIdx.x;
    int c8 = bid & 7, m = bid >> 3;
    int np = c8 * 64 + m / 6, r6 = m % 6;      // same A-panel -> same XCD
    int mat = r6 >> 1;
    int och0 = (r6 & 1) * 128;
    int n0 = np * 2;
    const unsigned short* W = (const unsigned short*)ws + (size_t)mat * 131072;
    const float* bnm = (const float*)(ws + WS_BN) + mat * 512;
    unsigned short* outp = (unsigned short*)(ws + WS_THQ + (size_t)mat * 33554432u);
    const unsigned short* X = (mat == 0) ? qT : (const unsigned short*)(ws + WS_CTX2);
    int t = threadIdx.x, w = t >> 6, l = t & 63, g = l >> 4, li = l & 15;
    int wr = w >> 1, wc = w & 1;

    float sc[4], sh[4];
#pragma unroll
    for (int nti = 0; nti < 4; ++nti) {
        int och = och0 + wc * 64 + nti * 16 + li;
        sc[nti] = bnm[och];
        sh[nti] = bnm[256 + och];
    }

    f32x4 acc[4][4];
#pragma unroll
    for (int mt = 0; mt < 4; ++mt)
#pragma unroll
        for (int nti = 0; nti < 4; ++nti) acc[mt][nti] = (f32x4){0.f, 0.f, 0.f, 0.f};

    // A tile: 128 rows x 32k = 512 x 16B chunks; slot = ch^((row>>1)&3)
    auto STAGE = [&](int kt) {
        int s = kt % 3;
        unsigned short* Ab = lds + s * 4096;
        unsigned short* Bb = lds + 12288 + s * 4096;
#pragma unroll
        for (int it = 0; it < 2; ++it) {
            int ci = it * 256 + t;
            int row = ci >> 2, ch = ci & 3;
            int nn = n0 + (row >> 6), q = row & 63;
            const unsigned short* src = X + (size_t)nn * 32768 + (size_t)q * 512 + kt * 32 + ((ch ^ ((row >> 1) & 3)) << 3);
            __builtin_amdgcn_global_load_lds(
                (const __attribute__((address_space(1))) void*)src,
                (__attribute__((address_space(3))) void*)(Ab + ci * 8), 16, 0, 0);
        }
#pragma unroll
        for (int it = 0; it < 2; ++it) {
            int ci = it * 256 + t;
            int row = ci >> 2, ch = ci & 3;
            const unsigned short* src = W + (size_t)(och0 + row) * 512 + kt * 32 + ((ch ^ ((row >> 1) & 3)) << 3);
            __builtin_amdgcn_global_load_lds(
                (const __attribute__((address_space(1))) void*)src,
                (__attribute__((address_space(3))) void*)(Bb + ci * 8), 16, 0, 0);
        }
    };
    auto COMPUTE = [&](int s) {
        const char* Ab = (const char*)(lds + s * 4096);
        const char* Bb = (const char*)(lds + 12288 + s * 4096);
        bf16x8 a[4], b[4];
#pragma unroll
        for (int mt = 0; mt < 4; ++mt) {
            int row = wr * 64 + mt * 16 + li;
            a[mt] = *(const bf16x8*)(Ab + row * 64 + (((g ^ ((row >> 1) & 3))) << 4));
        }
#pragma unroll
        for (int nti = 0; nti < 4; ++nti) {
            int br = wc * 64 + nti * 16 + li;
            b[nti] = *(const bf16x8*)(Bb + br * 64 + (((g ^ ((br >> 1) & 3))) << 4));
        }
        __builtin_amdgcn_s_setprio(1);
#pragma unroll
        for (int mt = 0; mt < 4; ++mt)
#pragma unroll
            for (int nti = 0; nti < 4; ++nti)
                acc[mt][nti] = MFMA16(a[mt], b[nti], acc[mt][nti]);
        __builtin_amdgcn_s_setprio(0);
    };

    STAGE(0);
    STAGE(1);
#pragma unroll 1
    for (int kt = 0; kt < 16; ++kt) {
        if (kt == 15) { asm volatile("s_waitcnt vmcnt(0)" ::: "memory"); }
        else          { asm volatile("s_waitcnt vmcnt(4)" ::: "memory"); }
        __builtin_amdgcn_s_barrier();
        __builtin_amdgcn_sched_barrier(0);
        if (kt < 14) STAGE(kt + 2);
        COMPUTE(kt % 3);
    }
    __syncthreads();   // all waves done reading frags before lds reuse

    unsigned short* stg = lds;
    if (mat != 2) {
        // ---- theta/phi: [128 Mrow][132] -> head-major [n][h][q][4d] ----
#pragma unroll
        for (int mt = 0; mt < 4; ++mt)
#pragma unroll
            for (int nti = 0; nti < 4; ++nti)
#pragma unroll
                for (int rr = 0; rr < 4; ++rr) {
                    int mrow = wr * 64 + mt * 16 + g * 4 + rr;
                    int ocl = wc * 64 + nti * 16 + li;
                    float v = fmaxf(acc[mt][nti][rr] * sc[nti] + sh[nti], 0.f);
                    stg[mrow * 132 + ocl] = f2bf(v);
                }
        __syncthreads();
#pragma unroll
        for (int it = 0; it < 8; ++it) {
            int ci = it * 256 + t;
            int s = ci >> 5, e = ci & 31;
            int nl = s >> 5, hl = s & 31;
            int q0 = e * 2;
            uint2 v0 = *(const uint2*)&stg[(nl * 64 + q0) * 132 + hl * 4];
            uint2 v1 = *(const uint2*)&stg[(nl * 64 + q0 + 1) * 132 + hl * 4];
            uint4 o; o.x = v0.x; o.y = v0.y; o.z = v1.x; o.w = v1.y;
            unsigned short* dst = outp + (size_t)(n0 + nl) * 16384 + (size_t)((och0 >> 2) + hl) * 256 + q0 * 4;
            *(uint4*)dst = o;
        }
    } else {
        // ---- g: transposed stg [128 och][136] -> d-major [n][h][d][k] ----
#pragma unroll
        for (int mt = 0; mt < 4; ++mt)
#pragma unroll
            for (int nti = 0; nti < 4; ++nti)
#pragma unroll
                for (int rr = 0; rr < 4; ++rr) {
                    int mrow = wr * 64 + mt * 16 + g * 4 + rr;
                    int ocl = wc * 64 + nti * 16 + li;
                    float v = fmaxf(acc[mt][nti][rr] * sc[nti] + sh[nti], 0.f);
                    stg[ocl * 136 + mrow] = f2bf(v);
                }
        __syncthreads();
#pragma unroll
        for (int it = 0; it < 8; ++it) {
            int ci = it * 256 + t;
            int nl = (ci >> 10) & 1, hl = (ci >> 5) & 31, dd = (ci >> 3) & 3, q8 = ci & 7;
            uint4 o = *(const uint4*)&stg[(hl * 4 + dd) * 136 + nl * 64 + q8 * 8];
            unsigned short* dst = outp + (size_t)(n0 + nl) * 16384 + (size_t)((och0 >> 2) + hl) * 256 + dd * 64 + q8 * 8;
            *(uint4*)dst = o;
        }
    }
}

// ---------------------------------------------------------------------------
// k3: attention.  One wave per (n, head-batch of 8); wave-private LDS (no
// barriers).  QK^T mfma -> no-max softmax (P=exp2(S*c-46); S>=0 from ReLU)
// -> cvt_pk bf16 -> LDS [q][k] (16B-chunk XOR) -> PV mfma(A=g^T d-major,
// B=P^T) -> rs-scale + uint2 store head-major.
// ---------------------------------------------------------------------------
__global__ __launch_bounds__(256) void k3_attn(char* __restrict__ ws) {
    __shared__ __align__(16) unsigned short plds[4][4096];  // per-wave P tile
    int n = blockIdx.x >> 1, half = blockIdx.x & 1;
    const unsigned short* th = (const unsigned short*)(ws + WS_THQ) + (size_t)n * 16384;
    const unsigned short* ph = (const unsigned short*)(ws + WS_THQ + 33554432u) + (size_t)n * 16384;
    const unsigned short* gx = (const unsigned short*)(ws + WS_THQ + 67108864u) + (size_t)n * 16384;
    unsigned short* yout = (unsigned short*)(ws + WS_YHM) + (size_t)n * 16384;
    int t = threadIdx.x, w = t >> 6, l = t & 63, g = l >> 4, li = l & 15;
    unsigned short* pw = &plds[w][0];
    const float Cs = 0.72134752044f;  // 0.5 (=1/sqrt(dim)) * log2(e)
    f32x4 z4 = {0.f, 0.f, 0.f, 0.f};
    bool zz = (g == 0);
    union FU { uint4 u; bf16x8 v8; };

#pragma unroll 1
    for (int hi = 0; hi < 8; ++hi) {
        int h = half * 32 + w * 8 + hi;
        const unsigned short* th_h = th + h * 256;
        const unsigned short* ph_h = ph + h * 256;
        const unsigned short* gx_h = gx + h * 256;   // [d][k] d-major
        bf16x8 a[4], b[4];
#pragma unroll
        for (int mt = 0; mt < 4; ++mt) {   // A = phi rows (k_sp); d at j=0..3, g==0 only
            uint2 v = *(const uint2*)(ph_h + (mt * 16 + li) * 4);
            FU f;
            f.u.x = zz ? v.x : 0u;
            f.u.y = zz ? v.y : 0u;
            f.u.z = 0u; f.u.w = 0u;
            a[mt] = f.v8;
        }
#pragma unroll
        for (int nt = 0; nt < 4; ++nt) {   // B = theta cols (q); only k<4 (g'==0) read
            uint2 v = *(const uint2*)(th_h + (nt * 16 + li) * 4);
            FU f;
            f.u.x = v.x; f.u.y = v.y; f.u.z = 0u; f.u.w = 0u;
            b[nt] = f.v8;
        }
        f32x4 p[4][4];
#pragma unroll
        for (int mt = 0; mt < 4; ++mt)
#pragma unroll
            for (int nt = 0; nt < 4; ++nt) p[mt][nt] = MFMA16(a[mt], b[nt], z4);
        // p[mt][nt][rr] = S[q=nt*16+li][k=mt*16+4g+rr], S >= 0.

        // ---- softmax denom (no max: P = exp2(S*Cs - 46); shift cancels) ----
        float rs[4];
#pragma unroll
        for (int nt = 0; nt < 4; ++nt) {
#pragma unroll
            for (int mt = 0; mt < 4; ++mt) {
                f32x4 tv = p[mt][nt] * Cs + (-46.0f);   // vector fma (v_pk_fma)
                f32x4 ev;
                ev[0] = __builtin_amdgcn_exp2f(tv[0]);
                ev[1] = __builtin_amdgcn_exp2f(tv[1]);
                ev[2] = __builtin_amdgcn_exp2f(tv[2]);
                ev[3] = __builtin_amdgcn_exp2f(tv[3]);
                p[mt][nt] = ev;
            }
            f32x4 s4 = (p[0][nt] + p[1][nt]) + (p[2][nt] + p[3][nt]);
            float sum = (s4[0] + s4[1]) + (s4[2] + s4[3]);
            sum += __shfl_xor(sum, 16);
            sum += __shfl_xor(sum, 32);
            rs[nt] = __builtin_amdgcn_rcpf(sum);
        }

        // ---- P -> bf16 -> wave-private LDS [q][128B], 16B-chunk XOR (q&7) ----
#pragma unroll
        for (int mt = 0; mt < 4; ++mt)
#pragma unroll
            for (int nt = 0; nt < 4; ++nt) {
                int q = nt * 16 + li;
                uint2 dv;
                dv.x = cvtpk(p[mt][nt][0], p[mt][nt][1]);
                dv.y = cvtpk(p[mt][nt][2], p[mt][nt][3]);
                int c16w = 2 * mt + (g >> 1);
                int byt = q * 128 + (((c16w ^ (q & 7)) << 4)) + ((g & 1) << 3);
                *(uint2*)((char*)pw + byt) = dv;
            }

        // ---- PV: y^T[d][q] = mfma(A=g^T[d][k] (global, d-major), B=P^T) ----
        bf16x8 afr0 = *(const bf16x8*)(gx_h + (li & 3) * 64 + g * 8);        // k=0..31
        bf16x8 afr1 = *(const bf16x8*)(gx_h + (li & 3) * 64 + 32 + g * 8);   // k=32..63
        f32x4 yv[4];
#pragma unroll
        for (int qt = 0; qt < 4; ++qt) {
            int q = qt * 16 + li;
            bf16x8 b0 = *(const bf16x8*)((const char*)pw + q * 128 + (((g) ^ (q & 7)) << 4));
            bf16x8 b1 = *(const bf16x8*)((const char*)pw + q * 128 + (((4 + g) ^ (q & 7)) << 4));
            f32x4 acc = MFMA16(afr0, b0, z4);
            acc = MFMA16(afr1, b1, acc);
            yv[qt] = acc;   // lanes 0..15: yv[qt][rr] = y[d=rr][q=qt*16+l]
        }

        if (l < 16) {
#pragma unroll
            for (int qt = 0; qt < 4; ++qt) {
                float s = rs[qt];
                uint2 pk;
                pk.x = cvtpk(yv[qt][0] * s, yv[qt][1] * s);
                pk.y = cvtpk(yv[qt][2] * s, yv[qt][3] * s);
                *(uint2*)(yout + h * 256 + (qt * 16 + l) * 4) = pk;
            }
        }
    }
}

// ---------------------------------------------------------------------------
// k4: out = query + ReLU(BN(out_W @ y)).  Grid = (n, och-half): 2048 blocks.
// Direct float4 epilogue, no transpose, one barrier total.
// ---------------------------------------------------------------------------
__global__ __launch_bounds__(256) void k4_out(const float* __restrict__ query,
                                              char* __restrict__ ws,
                                              float* __restrict__ out) {
    __shared__ __align__(16) unsigned short yA[64 * 256];
    int n = blockIdx.x >> 1, half = blockIdx.x & 1;
    const unsigned short* yQ = (const unsigned short*)(ws + WS_YHM) + (size_t)n * 16384;
    const unsigned short* W = (const unsigned short*)ws + (size_t)3 * 131072;  // out_W bf16
    const float* bn = (const float*)(ws + WS_BN) + 1536;
    int t = threadIdx.x, w = t >> 6, l = t & 63, g = l >> 4, li = l & 15;
    int ochb = half * 256;

#pragma unroll
    for (int it = 0; it < 8; ++it) {
        int ci = it * 256 + t;
        *(uint4*)((char*)yA + ci * 16) = *(const uint4*)(yQ + ci * 8);
    }
    __syncthreads();

    f32x4 acc[4][4];
#pragma unroll
    for (int mt = 0; mt < 4; ++mt)
#pragma unroll
        for (int nti = 0; nti < 4; ++nti) acc[mt][nti] = (f32x4){0.f, 0.f, 0.f, 0.f};

#pragma unroll 1
    for (int kt = 0; kt < 4; ++kt) {
        bf16x8 a[4][2];
#pragma unroll
        for (int mt = 0; mt < 4; ++mt) {
            int q = mt * 16 + li;
            const char* base = (const char*)yA;
            int c0 = kt * 8 + g, c1 = kt * 8 + 4 + g;
            union U { uint2 u[2]; bf16x8 v; };
            U u0, u1;
            u0.u[0] = *(const uint2*)(base + c0 * 1024 + q * 8);
            u0.u[1] = *(const uint2*)(base + c0 * 1024 + 512 + q * 8);
            u1.u[0] = *(const uint2*)(base + c1 * 1024 + q * 8);
            u1.u[1] = *(const uint2*)(base + c1 * 1024 + 512 + q * 8);
            a[mt][0] = u0.v;
            a[mt][1] = u1.v;
        }
#pragma unroll
        for (int nti = 0; nti < 4; ++nti) {
            int och = ochb + w * 64 + nti * 16 + li;
            const unsigned short* wr = W + (size_t)och * 256 + kt * 64 + g * 8;
            bf16x8 b0 = *(const bf16x8*)wr;
            bf16x8 b1 = *(const bf16x8*)(wr + 32);
#pragma unroll
            for (int mt = 0; mt < 4; ++mt) {
                acc[mt][nti] = MFMA16(a[mt][0], b0, acc[mt][nti]);
                acc[mt][nti] = MFMA16(a[mt][1], b1, acc[mt][nti]);
            }
        }
    }

    // ---- epilogue: direct float4 (4 consecutive q per lane), no barriers ----
#pragma unroll
    for (int nti = 0; nti < 4; ++nti) {
        int och = ochb + w * 64 + nti * 16 + li;
        float sc = bn[och], sb = bn[512 + och];
#pragma unroll
        for (int mt = 0; mt < 4; ++mt) {
            int q0 = mt * 16 + 4 * g;
            size_t idx = (size_t)n * 32768 + (size_t)och * 64 + q0;
            float4 qv = *(const float4*)(query + idx);
            float4 ov;
            ov.x = qv.x + fmaxf(acc[mt][nti][0] * sc + sb, 0.f);
            ov.y = qv.y + fmaxf(acc[mt][nti][1] * sc + sb, 0.f);
            ov.z = qv.z + fmaxf(acc[mt][nti][2] * sc + sb, 0.f);
            ov.w = qv.w + fmaxf(acc[mt][nti][3] * sc + sb, 0.f);
            *(float4*)(out + idx) = ov;
        }
    }
}

// ---------------------------------------------------------------------------
extern "C" void kernel_launch(void* const* d_in, const int* in_sizes, int n_in,
                              void* d_out, int out_size, void* d_ws, size_t ws_size,
                              hipStream_t stream) {
    (void)in_sizes; (void)n_in; (void)out_size; (void)ws_size;
    const float* query   = (const float*)d_in[0];
    const float* context = (const float*)d_in[1];
    const float* pm_W    = (const float*)d_in[2];
    const float* pm_b    = (const float*)d_in[3];
    const float* g_W     = (const float*)d_in[4];
    const float* g_g     = (const float*)d_in[5];
    const float* g_b     = (const float*)d_in[6];
    const float* g_m     = (const float*)d_in[7];
    const float* g_v     = (const float*)d_in[8];
    const float* th_W    = (const float*)d_in[9];
    const float* th_g    = (const float*)d_in[10];
    const float* th_b    = (const float*)d_in[11];
    const float* th_m    = (const float*)d_in[12];
    const float* th_v    = (const float*)d_in[13];
    const float* ph_W    = (const float*)d_in[14];
    const float* ph_g    = (const float*)d_in[15];
    const float* ph_b    = (const float*)d_in[16];
    const float* ph_m    = (const float*)d_in[17];
    const float* ph_v    = (const float*)d_in[18];
    const float* o_W     = (const float*)d_in[19];
    const float* o_g     = (const float*)d_in[20];
    const float* o_b     = (const float*)d_in[21];
    const float* o_m     = (const float*)d_in[22];
    const float* o_v     = (const float*)d_in[23];
    char* ws = (char*)d_ws;
    unsigned short* qT = (unsigned short*)d_out;  // scratch; k4 rewrites d_out

    k0_prep<<<3082, 256, 0, stream>>>(ws, th_W, ph_W, g_W, o_W, pm_W,
                                      th_g, th_b, th_m, th_v,
                                      ph_g, ph_b, ph_m, ph_v,
                                      g_g, g_b, g_m, g_v,
                                      o_g, o_b, o_m, o_v);
    k1_posmix<<<4096, 256, 0, stream>>>(context, pm_b, query, qT, ws);
    k2_proj<<<3072, 256, 0, stream>>>(ws, qT);
    k3_attn<<<2048, 256, 0, stream>>>(ws);
    k4_out<<<2048, 256, 0, stream>>>(query, ws, (float*)d_out);
}